// Round 1
// baseline (255.958 us; speedup 1.0000x reference)
//
#include <hip/hip_runtime.h>

#define B_   16
#define C_   16
#define H_   192
#define W_   192
#define HID_ 128

typedef _Float16 half8 __attribute__((ext_vector_type(8)));
typedef float    f32x4 __attribute__((ext_vector_type(4)));

// ws layout (halves):
//   [0,     8192)  wh1[128][64]   (K padded 48->64 with zeros)
//   [8192, 24576)  wh2[128][128]
//   [24576,26624)  wh3[16][128]
// bytes 0..53248, then float alpha_new[16*192*192] at byte 53248
#define WH_HALVES      26624
#define ALPHA_BYTE_OFF 53248

__global__ __launch_bounds__(256) void prep_weights(
    const float* __restrict__ w1, const float* __restrict__ w2,
    const float* __restrict__ w3, _Float16* __restrict__ wh)
{
    int i = blockIdx.x * 256 + threadIdx.x;
    if (i < 8192) {
        int o = i >> 6, c = i & 63;
        wh[i] = (c < 48) ? (_Float16)w1[o * 48 + c] : (_Float16)0.f;
    } else if (i < 24576) {
        wh[i] = (_Float16)w2[i - 8192];
    } else if (i < WH_HALVES) {
        wh[i] = (_Float16)w3[i - 24576];
    }
}

__global__ __launch_bounds__(512) void ca_main(
    const float* __restrict__ x,
    const float* __restrict__ b1g, const float* __restrict__ b2g,
    const float* __restrict__ b3g,
    const float* __restrict__ fire,
    const _Float16* __restrict__ wh,
    float* __restrict__ out,
    float* __restrict__ alpha_out)
{
    __shared__ __align__(16) struct {
        float    xh[4][16][68];     // halo: 4 rows x 16 ch x 66(+2) cols
        _Float16 w1[128][64];
        _Float16 w2[128][128];
        _Float16 w3[16][128];
        float    b1[128], b2[128], b3[16];
        _Float16 y[128][64];        // reused as float xout[16][132] in epilogue
        _Float16 h[128][128];
    } s;

    const int tid = threadIdx.x;
    int bx = blockIdx.x;
    const int seg = bx % 3; bx /= 3;
    const int hp  = bx % 96;
    const int bb  = bx / 96;
    const int h0 = hp * 2, w0 = seg * 64;

    // ---- stage weights (contiguous 53248 B = 3328 uint4) ----
    {
        const uint4* src = (const uint4*)wh;
        uint4* dst = (uint4*)&s.w1[0][0];
        for (int i = tid; i < 3328; i += 512) dst[i] = src[i];
    }
    if (tid < 128) { s.b1[tid] = b1g[tid]; s.b2[tid] = b2g[tid]; }
    if (tid < 16)  { s.b3[tid] = b3g[tid]; }

    // ---- stage x halo: 4 rows x 16 ch x 66 cols (zero padded OOB) ----
    for (int i = tid; i < 4224; i += 512) {
        int r = i / 1056, rem = i % 1056;
        int c = rem / 66, j = rem % 66;
        int hh = h0 - 1 + r, ww = w0 - 1 + j;
        float v = 0.f;
        if (hh >= 0 && hh < H_ && ww >= 0 && ww < W_)
            v = x[(((size_t)bb * 16 + c) * 192 + hh) * 192 + ww];
        s.xh[r][c][j] = v;
    }
    __syncthreads();

    // ---- perception: y = [x, sobel_x, sobel_y], fp32 -> f16 ----
    {
        int px = tid & 127, cg = tid >> 7;
        int r = px >> 6, col = px & 63;
#pragma unroll
        for (int cc = 0; cc < 4; ++cc) {
            int c = cg * 4 + cc;
            float ctr = s.xh[r + 1][c][col + 1];
            float sx = ( (s.xh[r    ][c][col + 2] - s.xh[r    ][c][col])
                 + 2.f * (s.xh[r + 1][c][col + 2] - s.xh[r + 1][c][col])
                 +       (s.xh[r + 2][c][col + 2] - s.xh[r + 2][c][col]) ) * 0.125f;
            float sy = ( (s.xh[r + 2][c][col    ] - s.xh[r][c][col    ])
                 + 2.f * (s.xh[r + 2][c][col + 1] - s.xh[r][c][col + 1])
                 +       (s.xh[r + 2][c][col + 2] - s.xh[r][c][col + 2]) ) * 0.125f;
            s.y[px][c]      = (_Float16)ctr;
            s.y[px][16 + c] = (_Float16)sx;
            s.y[px][32 + c] = (_Float16)sy;
            s.y[px][48 + c] = (_Float16)0.f;   // K padding
        }
    }
    __syncthreads();

    const int lane = tid & 63;
    const int wave = tid >> 6;
    const int lr = lane & 15, lg = lane >> 4;
    const int px0 = wave * 16;

    const f32x4 vzero = {0.f, 0.f, 0.f, 0.f};
    f32x4 acc[8];

    // ================= Layer 1: y[16x64] @ w1^T -> h1[16x128] =================
    half8 a1[2];
    a1[0] = *(const half8*)&s.y[px0 + lr][lg * 8];
    a1[1] = *(const half8*)&s.y[px0 + lr][32 + lg * 8];
#pragma unroll
    for (int nb = 0; nb < 8; ++nb) acc[nb] = vzero;
#pragma unroll
    for (int nb = 0; nb < 8; ++nb) {
        half8 bf0 = *(const half8*)&s.w1[nb * 16 + lr][lg * 8];
        half8 bf1 = *(const half8*)&s.w1[nb * 16 + lr][32 + lg * 8];
        acc[nb] = __builtin_amdgcn_mfma_f32_16x16x32_f16(a1[0], bf0, acc[nb], 0, 0, 0);
        acc[nb] = __builtin_amdgcn_mfma_f32_16x16x32_f16(a1[1], bf1, acc[nb], 0, 0, 0);
    }
#pragma unroll
    for (int nb = 0; nb < 8; ++nb) {
        int o = nb * 16 + lr;
        float bias = s.b1[o];
#pragma unroll
        for (int rr = 0; rr < 4; ++rr) {
            float v = acc[nb][rr] + bias;
            v = fminf(fmaxf(v, 0.f), 6.f);
            s.h[px0 + lg * 4 + rr][o] = (_Float16)v;
        }
    }
    __syncthreads();   // all waves past reading s.y (reused as xout below)

    // ================= Layer 2: h1 @ w2^T -> h2 (in-place in s.h) =============
    half8 a2[4];
#pragma unroll
    for (int kb = 0; kb < 4; ++kb)
        a2[kb] = *(const half8*)&s.h[px0 + lr][kb * 32 + lg * 8];
#pragma unroll
    for (int nb = 0; nb < 8; ++nb) acc[nb] = vzero;
#pragma unroll
    for (int nb = 0; nb < 8; ++nb) {
#pragma unroll
        for (int kb = 0; kb < 4; ++kb) {
            half8 bf = *(const half8*)&s.w2[nb * 16 + lr][kb * 32 + lg * 8];
            acc[nb] = __builtin_amdgcn_mfma_f32_16x16x32_f16(a2[kb], bf, acc[nb], 0, 0, 0);
        }
    }
#pragma unroll
    for (int nb = 0; nb < 8; ++nb) {
        int o = nb * 16 + lr;
        float bias = s.b2[o];
#pragma unroll
        for (int rr = 0; rr < 4; ++rr) {
            float v = acc[nb][rr] + bias;
            v = fminf(fmaxf(v, 0.f), 6.f);
            s.h[px0 + lg * 4 + rr][o] = (_Float16)v;
        }
    }

    // ================= Layer 3: h2 @ w3^T -> dx[16x16] ========================
    half8 a3[4];
#pragma unroll
    for (int kb = 0; kb < 4; ++kb)
        a3[kb] = *(const half8*)&s.h[px0 + lr][kb * 32 + lg * 8];
    f32x4 acc3 = vzero;
#pragma unroll
    for (int kb = 0; kb < 4; ++kb) {
        half8 bf = *(const half8*)&s.w3[lr][kb * 32 + lg * 8];
        acc3 = __builtin_amdgcn_mfma_f32_16x16x32_f16(a3[kb], bf, acc3, 0, 0, 0);
    }

    // epilogue: x_new = x + dx * (fire <= 0.5); stage into LDS for coalesced out
    {
        float* xout = (float*)&s.y[0][0];      // [16][132]
        float b3v = s.b3[lr];
#pragma unroll
        for (int rr = 0; rr < 4; ++rr) {
            int px = px0 + lg * 4 + rr;
            int rrow = px >> 6, col = px & 63;
            float dxv = acc3[rr] + b3v;
            float xc = s.xh[1 + rrow][lr][col + 1];
            float fn = fire[(((size_t)bb) * 192 + h0 + rrow) * 192 + w0 + col];
            float xn = xc + ((fn <= 0.5f) ? dxv : 0.f);
            xout[lr * 132 + px] = xn;
        }
    }
    __syncthreads();

    // ---- coalesced store + alpha copy ----
    {
        const float* xout = (const float*)&s.y[0][0];
        int px = tid & 127;
        int rrow = px >> 6, col = px & 63;
#pragma unroll
        for (int it = 0; it < 4; ++it) {
            int c = it * 4 + (tid >> 7);
            float v = xout[c * 132 + px];
            out[(((size_t)bb * 16 + c) * 192 + h0 + rrow) * 192 + w0 + col] = v;
            if (c == 3)
                alpha_out[(((size_t)bb) * 192 + h0 + rrow) * 192 + w0 + col] = v;
        }
    }
}

__global__ __launch_bounds__(256) void ca_mask(
    const float* __restrict__ x,
    const float* __restrict__ alpha_new,
    float* __restrict__ out)
{
    int pix = blockIdx.x * 256 + threadIdx.x;   // exactly 16*192*192 threads
    int ww = pix % 192; int t = pix / 192;
    int hh = t % 192;   int bb = t / 192;
    float pre = -1e30f, post = -1e30f;
#pragma unroll
    for (int di = -1; di <= 1; ++di) {
        int nh = hh + di;
        if (nh < 0 || nh >= 192) continue;
#pragma unroll
        for (int dj = -1; dj <= 1; ++dj) {
            int nw = ww + dj;
            if (nw < 0 || nw >= 192) continue;
            pre  = fmaxf(pre,  x[(((size_t)bb * 16 + 3) * 192 + nh) * 192 + nw]);
            post = fmaxf(post, alpha_new[(((size_t)bb) * 192 + nh) * 192 + nw]);
        }
    }
    bool alive = (pre > 0.1f) && (post > 0.1f);
    if (alive) return;                 // life==1 -> out already holds x_new
#pragma unroll
    for (int c = 0; c < 16; ++c) {
        out[(((size_t)bb * 16 + c) * 192 + hh) * 192 + ww] = 0.f;
    }
}

extern "C" void kernel_launch(void* const* d_in, const int* in_sizes, int n_in,
                              void* d_out, int out_size, void* d_ws, size_t ws_size,
                              hipStream_t stream) {
    const float* x    = (const float*)d_in[0];
    const float* w1   = (const float*)d_in[1];
    const float* b1   = (const float*)d_in[2];
    const float* w2   = (const float*)d_in[3];
    const float* b2   = (const float*)d_in[4];
    const float* w3   = (const float*)d_in[5];
    const float* b3   = (const float*)d_in[6];
    const float* fire = (const float*)d_in[7];
    float* out = (float*)d_out;

    _Float16* wh     = (_Float16*)d_ws;
    float* alpha_new = (float*)((char*)d_ws + ALPHA_BYTE_OFF);

    prep_weights<<<104, 256, 0, stream>>>(w1, w2, w3, wh);
    ca_main<<<4608, 512, 0, stream>>>(x, b1, b2, b3, fire, wh, out, alpha_new);
    ca_mask<<<2304, 256, 0, stream>>>(x, alpha_new, out);
}

// Round 2
// 174.600 us; speedup vs baseline: 1.4660x; 1.4660x over previous
//
#include <hip/hip_runtime.h>

#define B_   16
#define C_   16
#define H_   192
#define W_   192
#define HID_ 128

typedef _Float16 half8 __attribute__((ext_vector_type(8)));
typedef float    f32x4 __attribute__((ext_vector_type(4)));

// ws layout (halves), FRAGMENT-ORDERED for conflict-free ds_read_b128:
//   L1: frag f = nb*2 + khalf   (nb 0..7)        halves [0, 8192)
//   L2: frag f = nb*4 + kb      (nb 0..7,kb 0..3) halves [8192, 24576)
//   L3: frag f = kb             (kb 0..3)         halves [24576, 26624)
//   element: wh[base + (f*64 + lane)*8 + j] = W[n = f_n*16 + (lane&15)][k = f_k*32 + (lane>>4)*8 + j]
// bytes 0..53248, then float alpha_new[16*192*192] at byte 53248
#define WH_HALVES      26624
#define ALPHA_BYTE_OFF 53248

__global__ __launch_bounds__(256) void prep_weights(
    const float* __restrict__ w1, const float* __restrict__ w2,
    const float* __restrict__ w3, _Float16* __restrict__ wh)
{
    int i = blockIdx.x * 256 + threadIdx.x;
    if (i >= WH_HALVES) return;
    int rem = i & 511;
    int l = rem >> 3, j = rem & 7;
    int lr = l & 15, lg = l >> 4;
    _Float16 v;
    if (i < 8192) {                       // L1: K padded 48->64
        int f = i >> 9;
        int nb = f >> 1, hh = f & 1;
        int o = nb * 16 + lr, k = hh * 32 + lg * 8 + j;
        v = (k < 48) ? (_Float16)w1[o * 48 + k] : (_Float16)0.f;
    } else if (i < 24576) {               // L2
        int f = (i - 8192) >> 9;
        int nb = f >> 2, kb = f & 3;
        v = (_Float16)w2[(nb * 16 + lr) * 128 + kb * 32 + lg * 8 + j];
    } else {                              // L3
        int kb = (i - 24576) >> 9;
        v = (_Float16)w3[lr * 128 + kb * 32 + lg * 8 + j];
    }
    wh[i] = v;
}

__global__ __launch_bounds__(512) void ca_main(
    const float* __restrict__ x,
    const float* __restrict__ b1g, const float* __restrict__ b2g,
    const float* __restrict__ b3g,
    const float* __restrict__ fire,
    const _Float16* __restrict__ wh,
    float* __restrict__ out,
    float* __restrict__ alpha_out)
{
    __shared__ __align__(16) struct {
        _Float16 w[WH_HALVES];      // fragment-ordered weights
        float    xh[4][16][68];     // halo: 4 rows x 16 ch x 66(+2) cols
        _Float16 h[8][16][136];     // per-wave hidden tile, padded stride 272B
        float    xout[16][133];     // epilogue staging (padded)
        float    b1[128], b2[128], b3[16];
    } s;

    const int tid = threadIdx.x;
    int bx = blockIdx.x;
    const int seg = bx % 3; bx /= 3;
    const int hp  = bx % 96;
    const int bb  = bx / 96;
    const int h0 = hp * 2, w0 = seg * 64;

    // ---- stage weights (contiguous 53248 B = 3328 uint4) ----
    {
        const uint4* src = (const uint4*)wh;
        uint4* dst = (uint4*)&s.w[0];
        for (int i = tid; i < 3328; i += 512) dst[i] = src[i];
    }
    if (tid < 128) { s.b1[tid] = b1g[tid]; s.b2[tid] = b2g[tid]; }
    if (tid < 16)  { s.b3[tid] = b3g[tid]; }

    // ---- stage x halo: 4 rows x 16 ch x 66 cols (zero padded OOB) ----
    for (int i = tid; i < 4224; i += 512) {
        int r = i / 1056, rem = i % 1056;
        int c = rem / 66, j = rem % 66;
        int hh = h0 - 1 + r, ww = w0 - 1 + j;
        float v = 0.f;
        if (hh >= 0 && hh < H_ && ww >= 0 && ww < W_)
            v = x[(((size_t)bb * 16 + c) * 192 + hh) * 192 + ww];
        s.xh[r][c][j] = v;
    }
    __syncthreads();

    const int lane = tid & 63;
    const int wave = tid >> 6;
    const int lr = lane & 15, lg = lane >> 4;
    const int px0 = wave * 16;

    const half8* wf = (const half8*)s.w;
    _Float16 (*hw)[136] = s.h[wave];

    // ---- perception A-frags directly in registers ----
    // a1[0]: k=0..31  -> lg0: ctr c0..7 | lg1: ctr c8..15 | lg2: sx c0..7 | lg3: sx c8..15
    // a1[1]: k=32..63 -> lg0: sy  c0..7 | lg1: sy  c8..15 | lg2,3: zero (K pad)
    half8 a1[2];
    {
        const int mypx = px0 + lr;           // this lane's A-row pixel
        const int pr = mypx >> 6, pc = mypx & 63;
        const int cb = (lg & 1) * 8;
        const bool loD = (lg < 2);
#pragma unroll
        for (int j = 0; j < 8; ++j) {
            int c = cb + j;
            float t0 = s.xh[pr    ][c][pc    ], t1 = s.xh[pr    ][c][pc + 1], t2 = s.xh[pr    ][c][pc + 2];
            float m0 = s.xh[pr + 1][c][pc    ], m1 = s.xh[pr + 1][c][pc + 1], m2 = s.xh[pr + 1][c][pc + 2];
            float d0 = s.xh[pr + 2][c][pc    ], d1 = s.xh[pr + 2][c][pc + 1], d2 = s.xh[pr + 2][c][pc + 2];
            float gx = ((t2 - t0) + 2.f * (m2 - m0) + (d2 - d0)) * 0.125f;
            float gy = ((d0 - t0) + 2.f * (d1 - t1) + (d2 - t2)) * 0.125f;
            a1[0][j] = loD ? (_Float16)m1 : (_Float16)gx;
            a1[1][j] = loD ? (_Float16)gy : (_Float16)0.f;
        }
    }

    const f32x4 vzero = {0.f, 0.f, 0.f, 0.f};
    f32x4 acc[8];

    // ================= Layer 1: y[16x64] @ w1^T -> h1[16x128] =================
#pragma unroll
    for (int nb = 0; nb < 8; ++nb) acc[nb] = vzero;
#pragma unroll
    for (int nb = 0; nb < 8; ++nb) {
        half8 bf0 = wf[(nb * 2    ) * 64 + lane];
        half8 bf1 = wf[(nb * 2 + 1) * 64 + lane];
        acc[nb] = __builtin_amdgcn_mfma_f32_16x16x32_f16(a1[0], bf0, acc[nb], 0, 0, 0);
        acc[nb] = __builtin_amdgcn_mfma_f32_16x16x32_f16(a1[1], bf1, acc[nb], 0, 0, 0);
    }
#pragma unroll
    for (int nb = 0; nb < 8; ++nb) {
        int o = nb * 16 + lr;
        float bias = s.b1[o];
#pragma unroll
        for (int rr = 0; rr < 4; ++rr) {
            float v = acc[nb][rr] + bias;
            v = fminf(fmaxf(v, 0.f), 6.f);
            hw[lg * 4 + rr][o] = (_Float16)v;    // wave-private: no barrier
        }
    }

    // ================= Layer 2: h1 @ w2^T -> h2 (in-place, wave-private) ======
    half8 a2[4];
#pragma unroll
    for (int kb = 0; kb < 4; ++kb)
        a2[kb] = *(const half8*)&hw[lr][kb * 32 + lg * 8];
#pragma unroll
    for (int nb = 0; nb < 8; ++nb) acc[nb] = vzero;
#pragma unroll
    for (int nb = 0; nb < 8; ++nb) {
#pragma unroll
        for (int kb = 0; kb < 4; ++kb) {
            half8 bf = wf[1024 + (nb * 4 + kb) * 64 + lane];
            acc[nb] = __builtin_amdgcn_mfma_f32_16x16x32_f16(a2[kb], bf, acc[nb], 0, 0, 0);
        }
    }
#pragma unroll
    for (int nb = 0; nb < 8; ++nb) {
        int o = nb * 16 + lr;
        float bias = s.b2[o];
#pragma unroll
        for (int rr = 0; rr < 4; ++rr) {
            float v = acc[nb][rr] + bias;
            v = fminf(fmaxf(v, 0.f), 6.f);
            hw[lg * 4 + rr][o] = (_Float16)v;
        }
    }

    // ================= Layer 3: h2 @ w3^T -> dx[16x16] ========================
    half8 a3[4];
#pragma unroll
    for (int kb = 0; kb < 4; ++kb)
        a3[kb] = *(const half8*)&hw[lr][kb * 32 + lg * 8];
    f32x4 acc3 = vzero;
#pragma unroll
    for (int kb = 0; kb < 4; ++kb) {
        half8 bf = wf[3072 + kb * 64 + lane];
        acc3 = __builtin_amdgcn_mfma_f32_16x16x32_f16(a3[kb], bf, acc3, 0, 0, 0);
    }

    // epilogue: x_new = x + dx * (fire <= 0.5); stage for coalesced store
    {
        float b3v = s.b3[lr];
#pragma unroll
        for (int rr = 0; rr < 4; ++rr) {
            int px = px0 + lg * 4 + rr;
            int rrow = px >> 6, col = px & 63;
            float dxv = acc3[rr] + b3v;
            float xc = s.xh[1 + rrow][lr][col + 1];
            float fn = fire[(((size_t)bb) * 192 + h0 + rrow) * 192 + w0 + col];
            float xn = xc + ((fn <= 0.5f) ? dxv : 0.f);
            s.xout[lr][px] = xn;
        }
    }
    __syncthreads();

    // ---- coalesced store + alpha copy ----
    {
        int px = tid & 127;
        int rrow = px >> 6, col = px & 63;
#pragma unroll
        for (int it = 0; it < 4; ++it) {
            int c = it * 4 + (tid >> 7);
            float v = s.xout[c][px];
            out[(((size_t)bb * 16 + c) * 192 + h0 + rrow) * 192 + w0 + col] = v;
            if (c == 3)
                alpha_out[(((size_t)bb) * 192 + h0 + rrow) * 192 + w0 + col] = v;
        }
    }
}

__global__ __launch_bounds__(256) void ca_mask(
    const float* __restrict__ x,
    const float* __restrict__ alpha_new,
    float* __restrict__ out)
{
    int pix = blockIdx.x * 256 + threadIdx.x;   // exactly 16*192*192 threads
    int ww = pix % 192; int t = pix / 192;
    int hh = t % 192;   int bb = t / 192;
    float pre = -1e30f, post = -1e30f;
#pragma unroll
    for (int di = -1; di <= 1; ++di) {
        int nh = hh + di;
        if (nh < 0 || nh >= 192) continue;
#pragma unroll
        for (int dj = -1; dj <= 1; ++dj) {
            int nw = ww + dj;
            if (nw < 0 || nw >= 192) continue;
            pre  = fmaxf(pre,  x[(((size_t)bb * 16 + 3) * 192 + nh) * 192 + nw]);
            post = fmaxf(post, alpha_new[(((size_t)bb) * 192 + nh) * 192 + nw]);
        }
    }
    bool alive = (pre > 0.1f) && (post > 0.1f);
    if (alive) return;                 // life==1 -> out already holds x_new
#pragma unroll
    for (int c = 0; c < 16; ++c) {
        out[(((size_t)bb * 16 + c) * 192 + hh) * 192 + ww] = 0.f;
    }
}

extern "C" void kernel_launch(void* const* d_in, const int* in_sizes, int n_in,
                              void* d_out, int out_size, void* d_ws, size_t ws_size,
                              hipStream_t stream) {
    const float* x    = (const float*)d_in[0];
    const float* w1   = (const float*)d_in[1];
    const float* b1   = (const float*)d_in[2];
    const float* w2   = (const float*)d_in[3];
    const float* b2   = (const float*)d_in[4];
    const float* w3   = (const float*)d_in[5];
    const float* b3   = (const float*)d_in[6];
    const float* fire = (const float*)d_in[7];
    float* out = (float*)d_out;

    _Float16* wh     = (_Float16*)d_ws;
    float* alpha_new = (float*)((char*)d_ws + ALPHA_BYTE_OFF);

    prep_weights<<<104, 256, 0, stream>>>(w1, w2, w3, wh);
    ca_main<<<4608, 512, 0, stream>>>(x, b1, b2, b3, fire, wh, out, alpha_new);
    ca_mask<<<2304, 256, 0, stream>>>(x, alpha_new, out);
}

// Round 3
// 93.387 us; speedup vs baseline: 2.7408x; 1.8696x over previous
//
#include <hip/hip_runtime.h>

#define B_   16
#define C_   16
#define H_   192
#define W_   192
#define HID_ 128

typedef _Float16 half8 __attribute__((ext_vector_type(8)));
typedef float    f32x4 __attribute__((ext_vector_type(4)));

// ws layout (halves), FRAGMENT-ORDERED for conflict-free ds_read_b128:
//   L1: frag f = nb*2 + khalf   (nb 0..7)         halves [0, 8192)
//   L2: frag f = nb*4 + kb      (nb 0..7,kb 0..3)  halves [8192, 24576)
//   L3: frag f = kb             (kb 0..3)          halves [24576, 26624)
//   element: wh[base + (f*64 + lane)*8 + j] = W[n = f_n*16 + (lane&15)][k = f_k*32 + (lane>>4)*8 + j]
#define WH_HALVES      26624
#define ALPHA_BYTE_OFF 53248

#define NTILES   2304        // 16 bb * 48 vtiles * 3 seg   (tile = 4 rows x 64 cols)
#define NBLOCKS  256
#define ITERS    9           // 2304 / 256

__global__ __launch_bounds__(256) void prep_weights(
    const float* __restrict__ w1, const float* __restrict__ w2,
    const float* __restrict__ w3, _Float16* __restrict__ wh)
{
    int i = blockIdx.x * 256 + threadIdx.x;
    if (i >= WH_HALVES) return;
    int rem = i & 511;
    int l = rem >> 3, j = rem & 7;
    int lr = l & 15, lg = l >> 4;
    _Float16 v;
    if (i < 8192) {                       // L1: K padded 48->64
        int f = i >> 9;
        int nb = f >> 1, hh = f & 1;
        int o = nb * 16 + lr, k = hh * 32 + lg * 8 + j;
        v = (k < 48) ? (_Float16)w1[o * 48 + k] : (_Float16)0.f;
    } else if (i < 24576) {               // L2
        int f = (i - 8192) >> 9;
        int nb = f >> 2, kb = f & 3;
        v = (_Float16)w2[(nb * 16 + lr) * 128 + kb * 32 + lg * 8 + j];
    } else {                              // L3
        int kb = (i - 24576) >> 9;
        v = (_Float16)w3[lr * 128 + kb * 32 + lg * 8 + j];
    }
    wh[i] = v;
}

// halo flat size: [6 rows][16 ch][68 cols(66 real + 2 pad)]
#define HALO_N   6528        // 6*16*68
#define PF_SLOTS 7           // ceil(6528/1024)

__device__ __forceinline__ void halo_issue(const float* __restrict__ x,
                                           int bb, int h0, int w0, int tid,
                                           float pf[PF_SLOTS])
{
#pragma unroll
    for (int k = 0; k < PF_SLOTS; ++k) {
        int idx = tid + k * 1024;
        float v = 0.f;
        if (idx < HALO_N) {
            int r = idx / 1088;            // 16*68
            int rem = idx % 1088;
            int c = rem / 68, j = rem % 68;
            int hh = h0 - 1 + r, ww = w0 - 1 + j;
            if (j < 66 && hh >= 0 && hh < H_ && ww >= 0 && ww < W_)
                v = x[(((size_t)bb * 16 + c) * 192 + hh) * 192 + ww];
        }
        pf[k] = v;
    }
}

__global__ __launch_bounds__(1024, 4) void ca_main(
    const float* __restrict__ x,
    const float* __restrict__ b1g, const float* __restrict__ b2g,
    const float* __restrict__ b3g,
    const float* __restrict__ fire,
    const _Float16* __restrict__ wh,
    float* __restrict__ out,
    float* __restrict__ alpha_out)
{
    __shared__ __align__(16) struct {
        _Float16 w[WH_HALVES];       // fragment-ordered weights (shared by 16 waves)
        float    xh[6][16][68];      // halo for current 4x64 tile
        _Float16 h[16][2048];        // per-wave 4KB frag buffer (h1 -> h2 -> xout)
        float    b1[128], b2[128], b3[16];
    } s;

    const int tid  = threadIdx.x;
    const int lane = tid & 63;
    const int wave = tid >> 6;
    const int lr = lane & 15, lg = lane >> 4;

    // ---- prologue: stage weights (contiguous 53248 B = 3328 uint4) ----
    {
        const uint4* src = (const uint4*)wh;
        uint4* dst = (uint4*)&s.w[0];
        for (int i = tid; i < 3328; i += 1024) dst[i] = src[i];
    }
    if (tid < 128) { s.b1[tid] = b1g[tid]; s.b2[tid] = b2g[tid]; }
    if (tid < 16)  { s.b3[tid] = b3g[tid]; }

    // ---- prologue: halo for tile 0 ----
    {
        int t = blockIdx.x;
        int bb = t / 144, rem = t % 144;
        int h0 = (rem / 3) * 4, w0 = (rem % 3) * 64;
        float pf[PF_SLOTS];
        halo_issue(x, bb, h0, w0, tid, pf);
        float* xf = &s.xh[0][0][0];
#pragma unroll
        for (int k = 0; k < PF_SLOTS; ++k) {
            int idx = tid + k * 1024;
            if (idx < HALO_N) xf[idx] = pf[k];
        }
    }
    __syncthreads();

    const half8* wf = (const half8*)s.w;
    _Float16* hh_ = &s.h[wave][0];
    const f32x4 vzero = {0.f, 0.f, 0.f, 0.f};

    for (int it = 0; it < ITERS; ++it) {
        int t = blockIdx.x + it * NBLOCKS;
        int bb = t / 144, rem = t % 144;
        int h0 = (rem / 3) * 4, w0 = (rem % 3) * 64;

        // ---- T14: issue next tile's halo loads into regs (use much later) ----
        float pf[PF_SLOTS];
        const bool have_next = (it + 1 < ITERS);
        if (have_next) {
            int tn = blockIdx.x + (it + 1) * NBLOCKS;
            int bbn = tn / 144, remn = tn % 144;
            halo_issue(x, bbn, (remn / 3) * 4, (remn % 3) * 64, tid, pf);
        }

        // ---- perception A-frags in registers (own 16 px) ----
        // a1[0]: lg0 ctr c0-7 | lg1 ctr c8-15 | lg2 sx c0-7 | lg3 sx c8-15
        // a1[1]: lg0 sy c0-7  | lg1 sy c8-15  | lg2,3 zero (K pad)
        half8 a1[2];
        {
            const int px = wave * 16 + lr;       // A-row pixel
            const int pr = px >> 6, pc = px & 63;
            const int cb = (lg & 1) * 8;
            const bool loD = (lg < 2);
#pragma unroll
            for (int j = 0; j < 8; ++j) {
                int c = cb + j;
                float t0 = s.xh[pr    ][c][pc], t1 = s.xh[pr    ][c][pc + 1], t2 = s.xh[pr    ][c][pc + 2];
                float m0 = s.xh[pr + 1][c][pc], m1 = s.xh[pr + 1][c][pc + 1], m2 = s.xh[pr + 1][c][pc + 2];
                float d0 = s.xh[pr + 2][c][pc], d1 = s.xh[pr + 2][c][pc + 1], d2 = s.xh[pr + 2][c][pc + 2];
                float gx = ((t2 - t0) + 2.f * (m2 - m0) + (d2 - d0)) * 0.125f;
                float gy = ((d0 - t0) + 2.f * (d1 - t1) + (d2 - t2)) * 0.125f;
                a1[0][j] = loD ? (_Float16)m1 : (_Float16)gx;
                a1[1][j] = loD ? (_Float16)gy : (_Float16)0.f;
            }
        }

        // ========== Layer 1: y[16x64] @ w1^T -> h1[16x128] (frag layout) ======
#pragma unroll
        for (int nb = 0; nb < 8; ++nb) {
            f32x4 acc = vzero;
            half8 bf0 = wf[(nb * 2    ) * 64 + lane];
            half8 bf1 = wf[(nb * 2 + 1) * 64 + lane];
            acc = __builtin_amdgcn_mfma_f32_16x16x32_f16(a1[0], bf0, acc, 0, 0, 0);
            acc = __builtin_amdgcn_mfma_f32_16x16x32_f16(a1[1], bf1, acc, 0, 0, 0);
            float bias = s.b1[nb * 16 + lr];
            // value (px_loc = lg*4+rr, o = nb*16+lr) -> frag store
            int base = (nb >> 1) * 512 + ((((nb & 1) * 2 + (lr >> 3)) * 16 + lg * 4) * 8) + (lr & 7);
#pragma unroll
            for (int rr = 0; rr < 4; ++rr) {
                float v = acc[rr] + bias;
                v = fminf(fmaxf(v, 0.f), 6.f);
                hh_[base + rr * 8] = (_Float16)v;
            }
        }

        // ========== Layer 2: h1 @ w2^T -> h2 (reuse same frag buffer) =========
        half8 a2[4];
#pragma unroll
        for (int kb = 0; kb < 4; ++kb)
            a2[kb] = *(const half8*)&hh_[kb * 512 + lane * 8];
#pragma unroll
        for (int nb = 0; nb < 8; ++nb) {
            f32x4 acc = vzero;
#pragma unroll
            for (int kb = 0; kb < 4; ++kb) {
                half8 bf = wf[1024 + (nb * 4 + kb) * 64 + lane];
                acc = __builtin_amdgcn_mfma_f32_16x16x32_f16(a2[kb], bf, acc, 0, 0, 0);
            }
            float bias = s.b2[nb * 16 + lr];
            int base = (nb >> 1) * 512 + ((((nb & 1) * 2 + (lr >> 3)) * 16 + lg * 4) * 8) + (lr & 7);
#pragma unroll
            for (int rr = 0; rr < 4; ++rr) {
                float v = acc[rr] + bias;
                v = fminf(fmaxf(v, 0.f), 6.f);
                hh_[base + rr * 8] = (_Float16)v;
            }
        }

        // ========== Layer 3: h2 @ w3^T -> dx[16x16] ===========================
        half8 a3[4];
#pragma unroll
        for (int kb = 0; kb < 4; ++kb)
            a3[kb] = *(const half8*)&hh_[kb * 512 + lane * 8];
        f32x4 acc3 = vzero;
#pragma unroll
        for (int kb = 0; kb < 4; ++kb) {
            half8 bf = wf[3072 + kb * 64 + lane];
            acc3 = __builtin_amdgcn_mfma_f32_16x16x32_f16(a3[kb], bf, acc3, 0, 0, 0);
        }

        // ---- epilogue: x_new = x + dx*(fire<=0.5); stage into own h as f32 ----
        {
            float* xoutF = (float*)hh_;          // 256 floats: [co][px_loc]
            float b3v = s.b3[lr];                // co = lr
#pragma unroll
            for (int rr = 0; rr < 4; ++rr) {
                int pl = lg * 4 + rr;
                int px = wave * 16 + pl;
                int prow = px >> 6, pcol = px & 63;
                float dxv = acc3[rr] + b3v;
                float xc = s.xh[1 + prow][lr][1 + pcol];
                float fn = fire[(((size_t)bb) * 192 + h0 + prow) * 192 + w0 + pcol];
                float xn = xc + ((fn <= 0.5f) ? dxv : 0.f);
                xoutF[lr * 16 + pl] = xn;
            }
        }
        __syncthreads();

        // ---- coalesced store + alpha copy (reads all waves' xout) ----
#pragma unroll
        for (int k2 = 0; k2 < 4; ++k2) {
            int f = tid + k2 * 1024;             // 4096 = 16 ch * 256 px
            int c = f >> 8, px = f & 255;
            int wv = px >> 4, pl = px & 15;
            float v = ((const float*)&s.h[wv][0])[c * 16 + pl];
            int prow = px >> 6, pcol = px & 63;
            out[(((size_t)bb * 16 + c) * 192 + h0 + prow) * 192 + w0 + pcol] = v;
            if (c == 3)
                alpha_out[(((size_t)bb) * 192 + h0 + prow) * 192 + w0 + pcol] = v;
        }
        __syncthreads();

        // ---- write prefetched next halo to LDS ----
        if (have_next) {
            float* xf = &s.xh[0][0][0];
#pragma unroll
            for (int k = 0; k < PF_SLOTS; ++k) {
                int idx = tid + k * 1024;
                if (idx < HALO_N) xf[idx] = pf[k];
            }
            __syncthreads();
        }
    }
}

__global__ __launch_bounds__(256) void ca_mask(
    const float* __restrict__ x,
    const float* __restrict__ alpha_new,
    float* __restrict__ out)
{
    int pix = blockIdx.x * 256 + threadIdx.x;   // exactly 16*192*192 threads
    int ww = pix % 192; int t = pix / 192;
    int hh = t % 192;   int bb = t / 192;
    float pre = -1e30f, post = -1e30f;
#pragma unroll
    for (int di = -1; di <= 1; ++di) {
        int nh = hh + di;
        if (nh < 0 || nh >= 192) continue;
#pragma unroll
        for (int dj = -1; dj <= 1; ++dj) {
            int nw = ww + dj;
            if (nw < 0 || nw >= 192) continue;
            pre  = fmaxf(pre,  x[(((size_t)bb * 16 + 3) * 192 + nh) * 192 + nw]);
            post = fmaxf(post, alpha_new[(((size_t)bb) * 192 + nh) * 192 + nw]);
        }
    }
    bool alive = (pre > 0.1f) && (post > 0.1f);
    if (alive) return;                 // life==1 -> out already holds x_new
#pragma unroll
    for (int c = 0; c < 16; ++c) {
        out[(((size_t)bb * 16 + c) * 192 + hh) * 192 + ww] = 0.f;
    }
}

extern "C" void kernel_launch(void* const* d_in, const int* in_sizes, int n_in,
                              void* d_out, int out_size, void* d_ws, size_t ws_size,
                              hipStream_t stream) {
    const float* x    = (const float*)d_in[0];
    const float* w1   = (const float*)d_in[1];
    const float* b1   = (const float*)d_in[2];
    const float* w2   = (const float*)d_in[3];
    const float* b2   = (const float*)d_in[4];
    const float* w3   = (const float*)d_in[5];
    const float* b3   = (const float*)d_in[6];
    const float* fire = (const float*)d_in[7];
    float* out = (float*)d_out;

    _Float16* wh     = (_Float16*)d_ws;
    float* alpha_new = (float*)((char*)d_ws + ALPHA_BYTE_OFF);

    prep_weights<<<104, 256, 0, stream>>>(w1, w2, w3, wh);
    ca_main<<<NBLOCKS, 1024, 0, stream>>>(x, b1, b2, b3, fire, wh, out, alpha_new);
    ca_mask<<<2304, 256, 0, stream>>>(x, alpha_new, out);
}

// Round 5
// 87.343 us; speedup vs baseline: 2.9305x; 1.0692x over previous
//
#include <hip/hip_runtime.h>

#define B_   16
#define C_   16
#define H_   192
#define W_   192
#define HID_ 128

typedef _Float16 half8 __attribute__((ext_vector_type(8)));
typedef _Float16 half4 __attribute__((ext_vector_type(4)));
typedef float    f32x4 __attribute__((ext_vector_type(4)));

// ws layout (halves), FRAGMENT-ORDERED for conflict-free ds_read_b128:
//   L1: frag f = nb*2 + khalf   (nb 0..7)         halves [0, 8192)
//   L2: frag f = nb*4 + kb      (nb 0..7,kb 0..3)  halves [8192, 24576)
//   L3: frag f = kb             (kb 0..3)          halves [24576, 26624)
//   element: wh[base + (f*64 + lane)*8 + j] = W[n = f_n*16 + (lane&15)][k = f_k*32 + (lane>>4)*8 + j]
// Same fragment serves as A-operand (rows = n): A and B lane maps are identical
// on gfx950 16x16x32 (row/col = lane&15, k = (lane>>4)*8 + j) — verified R3.
#define WH_HALVES      26624
#define ALPHA_BYTE_OFF 53248

#define NTILES   2304        // 16 bb * 48 vtiles * 3 seg   (tile = 4 rows x 64 cols)
#define NBLOCKS  256
#define ITERS    9           // 2304 / 256

__global__ __launch_bounds__(256) void prep_weights(
    const float* __restrict__ w1, const float* __restrict__ w2,
    const float* __restrict__ w3, _Float16* __restrict__ wh)
{
    int i = blockIdx.x * 256 + threadIdx.x;
    if (i >= WH_HALVES) return;
    int rem = i & 511;
    int l = rem >> 3, j = rem & 7;
    int lr = l & 15, lg = l >> 4;
    _Float16 v;
    if (i < 8192) {                       // L1: K padded 48->64
        int f = i >> 9;
        int nb = f >> 1, hh = f & 1;
        int o = nb * 16 + lr, k = hh * 32 + lg * 8 + j;
        v = (k < 48) ? (_Float16)w1[o * 48 + k] : (_Float16)0.f;
    } else if (i < 24576) {               // L2
        int f = (i - 8192) >> 9;
        int nb = f >> 2, kb = f & 3;
        v = (_Float16)w2[(nb * 16 + lr) * 128 + kb * 32 + lg * 8 + j];
    } else {                              // L3
        int kb = (i - 24576) >> 9;
        v = (_Float16)w3[lr * 128 + kb * 32 + lg * 8 + j];
    }
    wh[i] = v;
}

// halo flat size: [6 rows][16 ch][68 cols(66 real + 2 pad)]
#define HALO_N   6528        // 6*16*68
#define PF_SLOTS 7           // ceil(6528/1024)

__device__ __forceinline__ void halo_issue(const float* __restrict__ x,
                                           int bb, int h0, int w0, int tid,
                                           float pf[PF_SLOTS])
{
#pragma unroll
    for (int k = 0; k < PF_SLOTS; ++k) {
        int idx = tid + k * 1024;
        float v = 0.f;
        if (idx < HALO_N) {
            int r = idx / 1088;            // 16*68
            int rem = idx % 1088;
            int c = rem / 68, j = rem % 68;
            int hh = h0 - 1 + r, ww = w0 - 1 + j;
            if (j < 66 && hh >= 0 && hh < H_ && ww >= 0 && ww < W_)
                v = x[(((size_t)bb * 16 + c) * 192 + hh) * 192 + ww];
        }
        pf[k] = v;
    }
}

__global__ __launch_bounds__(1024, 4) void ca_main(
    const float* __restrict__ x,
    const float* __restrict__ b1g, const float* __restrict__ b2g,
    const float* __restrict__ b3g,
    const float* __restrict__ fire,
    const _Float16* __restrict__ wh,
    float* __restrict__ out,
    float* __restrict__ alpha_out)
{
    __shared__ __align__(16) struct {
        _Float16 w[WH_HALVES];       // fragment-ordered weights (all 16 waves share)
        float    xh[6][16][68];      // halo for current 4x64 tile
        _Float16 h[16][2048];        // per-wave 4KB: 16 rows x 256B, XOR-swizzled in-row
        float    b1[128], b2[128], b3[16];
    } s;

    const int tid  = threadIdx.x;
    const int lane = tid & 63;
    const int wave = tid >> 6;
    const int lr = lane & 15, hi = lane >> 4;

    // ---- prologue: stage weights (contiguous 53248 B = 3328 uint4) ----
    {
        const uint4* src = (const uint4*)wh;
        uint4* dst = (uint4*)&s.w[0];
        for (int i = tid; i < 3328; i += 1024) dst[i] = src[i];
    }
    if (tid < 128) { s.b1[tid] = b1g[tid]; s.b2[tid] = b2g[tid]; }
    if (tid < 16)  { s.b3[tid] = b3g[tid]; }

    // ---- prologue: halo for tile 0 ----
    {
        int t = blockIdx.x;
        int bb = t / 144, rem = t % 144;
        int h0 = (rem / 3) * 4, w0 = (rem % 3) * 64;
        float pf[PF_SLOTS];
        halo_issue(x, bb, h0, w0, tid, pf);
        float* xf = &s.xh[0][0][0];
#pragma unroll
        for (int k = 0; k < PF_SLOTS; ++k) {
            int idx = tid + k * 1024;
            if (idx < HALO_N) xf[idx] = pf[k];
        }
    }
    __syncthreads();

    const half8* wf = (const half8*)s.w;
    char* hb = (char*)&s.h[wave][0];
    const int rowb = lr * 256;           // row byte offset (128-aligned: XOR stays in-row)
    const int swz  = (lr & 3) << 5;      // in-row XOR swizzle, off^swz < 256 always

    for (int it = 0; it < ITERS; ++it) {
        int t = blockIdx.x + it * NBLOCKS;
        int bb = t / 144, rem = t % 144;
        int h0 = (rem / 3) * 4, w0 = (rem % 3) * 64;

        // this lane's pixel (B-operand column): px = wave*16 + lr
        const int px = wave * 16 + lr;
        const int prow = px >> 6, pcol = px & 63;

        // ---- T14: issue next tile's halo + this tile's fire early ----
        float pf[PF_SLOTS];
        const bool have_next = (it + 1 < ITERS);
        if (have_next) {
            int tn = blockIdx.x + (it + 1) * NBLOCKS;
            int bbn = tn / 144, remn = tn % 144;
            halo_issue(x, bbn, (remn / 3) * 4, (remn % 3) * 64, tid, pf);
        }
        const float fn = fire[(((size_t)bb) * 192 + h0 + prow) * 192 + w0 + pcol];

        // ---- perception B-frags in registers (own pixel, k = hi*8+j) ----
        // a1[0]: hi0 ctr c0-7 | hi1 ctr c8-15 | hi2 sx c0-7 | hi3 sx c8-15
        // a1[1]: hi0 sy c0-7  | hi1 sy c8-15  | hi2,3 zero (K pad)
        half8 a1[2];
        {
            const int cb = (hi & 1) * 8;
            const bool loD = (hi < 2);
#pragma unroll
            for (int j = 0; j < 8; ++j) {
                int c = cb + j;
                float t0 = s.xh[prow    ][c][pcol], t1 = s.xh[prow    ][c][pcol + 1], t2 = s.xh[prow    ][c][pcol + 2];
                float m0 = s.xh[prow + 1][c][pcol], m1 = s.xh[prow + 1][c][pcol + 1], m2 = s.xh[prow + 1][c][pcol + 2];
                float d0 = s.xh[prow + 2][c][pcol], d1 = s.xh[prow + 2][c][pcol + 1], d2 = s.xh[prow + 2][c][pcol + 2];
                float gx = ((t2 - t0) + 2.f * (m2 - m0) + (d2 - d0)) * 0.125f;
                float gy = ((d0 - t0) + 2.f * (d1 - t1) + (d2 - t2)) * 0.125f;
                a1[0][j] = loD ? (_Float16)m1 : (_Float16)gx;
                a1[1][j] = loD ? (_Float16)gy : (_Float16)0.f;
            }
        }

        // ========== Layer 1 (swapped): D[o][px] = W1 . y^T, bias in C-init ====
#pragma unroll
        for (int nb = 0; nb < 8; ++nb) {
            f32x4 acc = *(const f32x4*)&s.b1[nb * 16 + hi * 4];
            half8 bf0 = wf[(nb * 2    ) * 64 + lane];
            half8 bf1 = wf[(nb * 2 + 1) * 64 + lane];
            acc = __builtin_amdgcn_mfma_f32_16x16x32_f16(bf0, a1[0], acc, 0, 0, 0);
            acc = __builtin_amdgcn_mfma_f32_16x16x32_f16(bf1, a1[1], acc, 0, 0, 0);
            half4 hv;
#pragma unroll
            for (int rr = 0; rr < 4; ++rr)
                hv[rr] = (_Float16)fminf(fmaxf(acc[rr], 0.f), 6.f);
            *(half4*)(hb + rowb + ((nb * 32 + hi * 8) ^ swz)) = hv;   // o=nb*16+hi*4+rr
        }

        // ========== Layer 2 (swapped, in-place h) =============================
        half8 a2[4];
#pragma unroll
        for (int kb = 0; kb < 4; ++kb)
            a2[kb] = *(const half8*)(hb + rowb + ((kb * 64 + hi * 16) ^ swz));
#pragma unroll
        for (int nb = 0; nb < 8; ++nb) {
            f32x4 acc = *(const f32x4*)&s.b2[nb * 16 + hi * 4];
#pragma unroll
            for (int kb = 0; kb < 4; ++kb) {
                half8 bf = wf[1024 + (nb * 4 + kb) * 64 + lane];
                acc = __builtin_amdgcn_mfma_f32_16x16x32_f16(bf, a2[kb], acc, 0, 0, 0);
            }
            half4 hv;
#pragma unroll
            for (int rr = 0; rr < 4; ++rr)
                hv[rr] = (_Float16)fminf(fmaxf(acc[rr], 0.f), 6.f);
            *(half4*)(hb + rowb + ((nb * 32 + hi * 8) ^ swz)) = hv;
        }

        // ========== Layer 3 (swapped): dx[c][px], c = hi*4+rr =================
        half8 a3[4];
#pragma unroll
        for (int kb = 0; kb < 4; ++kb)
            a3[kb] = *(const half8*)(hb + rowb + ((kb * 64 + hi * 16) ^ swz));
        f32x4 acc3 = *(const f32x4*)&s.b3[hi * 4];
#pragma unroll
        for (int kb = 0; kb < 4; ++kb) {
            half8 bf = wf[3072 + kb * 64 + lane];
            acc3 = __builtin_amdgcn_mfma_f32_16x16x32_f16(bf, a3[kb], acc3, 0, 0, 0);
        }

        // ---- epilogue: 4 channels of this lane's pixel, direct global store --
        {
            const bool upd = (fn <= 0.5f);
            size_t obase = (((size_t)bb * 16) * 192 + h0 + prow) * 192 + w0 + pcol;
#pragma unroll
            for (int rr = 0; rr < 4; ++rr) {
                int c = hi * 4 + rr;
                float xc = s.xh[1 + prow][c][1 + pcol];
                float xn = xc + (upd ? acc3[rr] : 0.f);
                out[obase + (size_t)c * 36864] = xn;
                if (rr == 3 && hi == 0)   // c == 3: alpha
                    alpha_out[(((size_t)bb) * 192 + h0 + prow) * 192 + w0 + pcol] = xn;
            }
        }
        __syncthreads();                  // all lanes done reading s.xh

        // ---- write prefetched next halo to LDS ----
        if (have_next) {
            float* xf = &s.xh[0][0][0];
#pragma unroll
            for (int k = 0; k < PF_SLOTS; ++k) {
                int idx = tid + k * 1024;
                if (idx < HALO_N) xf[idx] = pf[k];
            }
            __syncthreads();
        }
    }
}

__global__ __launch_bounds__(256) void ca_mask(
    const float* __restrict__ x,
    const float* __restrict__ alpha_new,
    float* __restrict__ out)
{
    int pix = blockIdx.x * 256 + threadIdx.x;   // exactly 16*192*192 threads
    int ww = pix % 192; int t = pix / 192;
    int hh = t % 192;   int bb = t / 192;
    float pre = -1e30f, post = -1e30f;
#pragma unroll
    for (int di = -1; di <= 1; ++di) {
        int nh = hh + di;
        if (nh < 0 || nh >= 192) continue;
#pragma unroll
        for (int dj = -1; dj <= 1; ++dj) {
            int nw = ww + dj;
            if (nw < 0 || nw >= 192) continue;
            pre  = fmaxf(pre,  x[(((size_t)bb * 16 + 3) * 192 + nh) * 192 + nw]);
            post = fmaxf(post, alpha_new[(((size_t)bb) * 192 + nh) * 192 + nw]);
        }
    }
    bool alive = (pre > 0.1f) && (post > 0.1f);
    if (alive) return;                 // life==1 -> out already holds x_new
#pragma unroll
    for (int c = 0; c < 16; ++c) {
        out[(((size_t)bb * 16 + c) * 192 + hh) * 192 + ww] = 0.f;
    }
}

extern "C" void kernel_launch(void* const* d_in, const int* in_sizes, int n_in,
                              void* d_out, int out_size, void* d_ws, size_t ws_size,
                              hipStream_t stream) {
    const float* x    = (const float*)d_in[0];
    const float* w1   = (const float*)d_in[1];
    const float* b1   = (const float*)d_in[2];
    const float* w2   = (const float*)d_in[3];
    const float* b2   = (const float*)d_in[4];
    const float* w3   = (const float*)d_in[5];
    const float* b3   = (const float*)d_in[6];
    const float* fire = (const float*)d_in[7];
    float* out = (float*)d_out;

    _Float16* wh     = (_Float16*)d_ws;
    float* alpha_new = (float*)((char*)d_ws + ALPHA_BYTE_OFF);

    prep_weights<<<104, 256, 0, stream>>>(w1, w2, w3, wh);
    ca_main<<<NBLOCKS, 1024, 0, stream>>>(x, b1, b2, b3, fire, wh, out, alpha_new);
    ca_mask<<<2304, 256, 0, stream>>>(x, alpha_new, out);
}